// Round 7
// baseline (143.140 us; speedup 1.0000x reference)
//
#include <hip/hip_runtime.h>

#define EMB_DIM 256
#define HW 4096
#define N_EMB 1024
#define TOT_ELEMS (32 * HW * EMB_DIM)   // 33554432

typedef __attribute__((ext_vector_type(8))) short bf16x8;
typedef __attribute__((ext_vector_type(4))) float f32x4;

// ws layout (bytes)
#define WS_EMB_OFF 0              // 512 KB swizzled bf16 emb (32-e chunk layout)
#define WS_E2_OFF  524288         // 1024 f32 ||e||^2
#define WS_PSC_OFF 528384         // 512 f32 block partials

#define MAIN_BLOCKS 512           // 256 rows/block, 4 waves x 64 rows -> ALL resident (2/CU)

__device__ __forceinline__ unsigned short f2bf(float f) {
    unsigned int u = __builtin_bit_cast(unsigned int, f);
    u += 0x7FFFu + ((u >> 16) & 1u);   // round-to-nearest-even
    return (unsigned short)(u >> 16);
}

typedef const __attribute__((address_space(1))) unsigned int* gas_u32p;
typedef __attribute__((address_space(3))) unsigned int* las_u32p;
__device__ __forceinline__ void gll16(const void* g, void* l) {
    __builtin_amdgcn_global_load_lds((gas_u32p)g, (las_u32p)l, 16, 0, 0);
}

// ---------------------------------------------------------------------------
// Kernel 0: emb fp32 -> bf16, pre-swizzled 16KB-chunk layout + e2 = ||e||^2.
// chunk = e>>5 (32 e per 16KB chunk), row el = e&31 (512B rows),
// byte cb within row stored at cb ^ ((el&31)<<4).
// (verified R5/R6: correct + 0 LDS bank conflicts on the paired reader)
// ---------------------------------------------------------------------------
__global__ __launch_bounds__(64) void prep_emb(const float* __restrict__ emb,
                                               unsigned long long* __restrict__ embsw,
                                               float* __restrict__ e2) {
    const int e = blockIdx.x, ln = threadIdx.x;
    const float4 v = reinterpret_cast<const float4*>(emb)[e * 64 + ln];
    float s = v.x * v.x + v.y * v.y + v.z * v.z + v.w * v.w;

    unsigned long long pk = (unsigned long long)f2bf(v.x)
                          | ((unsigned long long)f2bf(v.y) << 16)
                          | ((unsigned long long)f2bf(v.z) << 32)
                          | ((unsigned long long)f2bf(v.w) << 48);
    const int el = e & 31, ch = e >> 5;
    const int cb = ln * 8;
    const int off = (ch << 14) + (el << 9) + (cb ^ ((el & 31) << 4));
    *reinterpret_cast<unsigned long long*>(reinterpret_cast<char*>(embsw) + off) = pk;

#pragma unroll
    for (int o = 32; o; o >>= 1) s += __shfl_down(s, o);
    if (ln == 0) e2[e] = s;
}

// ---------------------------------------------------------------------------
// Kernel 1: fused copy + sum(x^2) + GEMM + min-reduction.
// 4 waves x 64 rows/wave (4 B-frag sets, 128 AGPRs pinned via asm "+a" —
// R4/R6-verified spill fix). 512 blocks = 2/CU, ALL resident: one IO phase,
// one compute phase (R6's 4 lock-stepped rounds summed their phases).
// Per chunk per wave: 16 ds_read_b128 -> 64 MFMA (4 indep chains/A-frag).
// emb: 16KB chunks double-buffered, global_load_lds from pre-swizzled source
// (0 bank conflicts verified). Prologue fenced per-kf: 32 loads in flight.
// MFMA 16x16x32 bf16: D[e][m]: m=lane&15, e=4*(lane>>4)+reg.
// ---------------------------------------------------------------------------
__global__ __launch_bounds__(256)
void vq_main(const float* __restrict__ x,
             float* __restrict__ out,
             const uint4* __restrict__ embsw,
             const float* __restrict__ e2,
             float* __restrict__ psc) {
    __shared__ uint4 smem4[2048];          // 2 x 16KB emb chunk buffers
    const int tid = threadIdx.x;
    const int wv = tid >> 6, ln = tid & 63;
    const int u = ln & 15, g = ln >> 4;    // m-lane, k-octet group

    const int row_base = blockIdx.x << 8;  // 256 rows/block
    const int b = row_base >> 12, n_base = row_base & 4095;
    const unsigned base0 = (unsigned)(b * (EMB_DIM * HW) + n_base + wv * 64 + u);

    // ---- stage emb chunk 0 (L2-resident; overlaps the x prologue) ----
    {
        const uint4* gs = embsw + wv * 256 + ln;
        char* lb = (char*)smem4 + wv * 4096;
#pragma unroll
        for (int i = 0; i < 4; ++i) gll16(gs + i * 64, lb + i * 1024);
    }

    // ---- load x once: copy to out, accumulate x^2, build 4 B-frag sets.
    //      Fenced per kf: 32 loads in flight caps register demand. ----
    float x2s = 0.f;
    bf16x8 bx[4][8];
#pragma unroll
    for (int kf = 0; kf < 8; ++kf) {
#pragma unroll
        for (int s = 0; s < 4; ++s) {
            bf16x8 v;
#pragma unroll
            for (int j = 0; j < 8; ++j) {
                const unsigned o = base0 + (unsigned)((kf * 32 + g * 8 + j) * HW + s * 16);
                const float f = x[o];
                out[o] = f;
                x2s += f * f;
                v[j] = (short)f2bf(f);
            }
            bx[s][kf] = v;
            // pin persistent fragments into AGPRs (R4/R6-verified: kills spills)
            asm volatile("" : "+a"(bx[s][kf]));
        }
        __builtin_amdgcn_sched_barrier(0);   // no load hoisting across kf groups
    }

    __syncthreads();   // chunk 0 staged (barrier drains vmcnt)

    const char* smemb = reinterpret_cast<const char*>(smem4);
    float b0 = 3.0e38f, b1 = 3.0e38f, b2 = 3.0e38f, b3 = 3.0e38f;

    for (int c = 0; c < 32; ++c) {
        if (c < 31) {  // stage next 16KB chunk into the other buffer
            const uint4* gs = embsw + (c + 1) * 1024 + wv * 256 + ln;
            char* lb = (char*)smem4 + ((c + 1) & 1) * 16384 + wv * 4096;
#pragma unroll
            for (int i = 0; i < 4; ++i) gll16(gs + i * 64, lb + i * 1024);
        }
        const char* bufb = smemb + (c & 1) * 16384;
#pragma unroll
        for (int t = 0; t < 2; ++t) {
            const int el = t * 16 + u;
            f32x4 a0 = {0.f, 0.f, 0.f, 0.f}, a1 = a0, a2 = a0, a3 = a0;
#pragma unroll
            for (int kf = 0; kf < 8; ++kf) {
                const int off = el * 512 + ((kf * 64 + g * 16) ^ ((el & 31) << 4));
                const bf16x8 a = *reinterpret_cast<const bf16x8*>(bufb + off);
                a0 = __builtin_amdgcn_mfma_f32_16x16x32_bf16(a, bx[0][kf], a0, 0, 0, 0);
                a1 = __builtin_amdgcn_mfma_f32_16x16x32_bf16(a, bx[1][kf], a1, 0, 0, 0);
                a2 = __builtin_amdgcn_mfma_f32_16x16x32_bf16(a, bx[2][kf], a2, 0, 0, 0);
                a3 = __builtin_amdgcn_mfma_f32_16x16x32_bf16(a, bx[3][kf], a3, 0, 0, 0);
            }
            const f32x4 ev = *reinterpret_cast<const f32x4*>(e2 + c * 32 + t * 16 + g * 4);
#pragma unroll
            for (int r = 0; r < 4; ++r) {
                b0 = fminf(b0, fmaf(-2.f, a0[r], ev[r]));
                b1 = fminf(b1, fmaf(-2.f, a1[r], ev[r]));
                b2 = fminf(b2, fmaf(-2.f, a2[r], ev[r]));
                b3 = fminf(b3, fmaf(-2.f, a3[r], ev[r]));
            }
        }
        __syncthreads();   // all waves done with bufb; gll(c+1) drained
    }

    // combine the 4 g-lane copies (each saw a disjoint quarter of the e's)
    b0 = fminf(b0, __shfl_xor(b0, 16));
    b0 = fminf(b0, __shfl_xor(b0, 32));
    b1 = fminf(b1, __shfl_xor(b1, 16));
    b1 = fminf(b1, __shfl_xor(b1, 32));
    b2 = fminf(b2, __shfl_xor(b2, 16));
    b2 = fminf(b2, __shfl_xor(b2, 32));
    b3 = fminf(b3, __shfl_xor(b3, 16));
    b3 = fminf(b3, __shfl_xor(b3, 32));

    float contrib = x2s + ((g == 0) ? ((b0 + b1) + (b2 + b3)) : 0.f);
#pragma unroll
    for (int o = 32; o; o >>= 1) contrib += __shfl_down(contrib, o);

    float* wsf = reinterpret_cast<float*>(smem4);   // safe: post-loop barrier
    if (ln == 0) wsf[wv] = contrib;
    __syncthreads();
    if (tid == 0) psc[blockIdx.x] = (wsf[0] + wsf[1]) + (wsf[2] + wsf[3]);
}

// ---------------------------------------------------------------------------
// Kernel 2: deterministic tree-reduce of partials -> loss scalar.
// ---------------------------------------------------------------------------
__global__ __launch_bounds__(256) void finalize(const float* __restrict__ psc,
                                                float* __restrict__ out_loss) {
    __shared__ float red[256];
    const int t = threadIdx.x;
    float s = 0.f;
#pragma unroll
    for (int i = 0; i < MAIN_BLOCKS / 256; ++i) s += psc[t + i * 256];
    red[t] = s;
    __syncthreads();
    for (int h = 128; h; h >>= 1) {
        if (t < h) red[t] += red[t + h];
        __syncthreads();
    }
    if (t == 0) *out_loss = 1.25f * red[0] / (float)TOT_ELEMS;
}

extern "C" void kernel_launch(void* const* d_in, const int* in_sizes, int n_in,
                              void* d_out, int out_size, void* d_ws, size_t ws_size,
                              hipStream_t stream) {
    const float* x = (const float*)d_in[0];
    const float* emb = (const float*)d_in[1];
    float* out = (float*)d_out;
    char* ws = (char*)d_ws;

    unsigned long long* embsw = (unsigned long long*)(ws + WS_EMB_OFF);
    float* e2  = (float*)(ws + WS_E2_OFF);
    float* psc = (float*)(ws + WS_PSC_OFF);

    prep_emb<<<N_EMB, 64, 0, stream>>>(emb, embsw, e2);
    vq_main<<<MAIN_BLOCKS, 256, 0, stream>>>(x, out, (const uint4*)(ws + WS_EMB_OFF), e2, psc);
    finalize<<<1, 256, 0, stream>>>(psc, out + TOT_ELEMS);
}

// Round 8
// 87.377 us; speedup vs baseline: 1.6382x; 1.6382x over previous
//
#include <hip/hip_runtime.h>

#define EMB_DIM 256
#define HW 4096
#define N_EMB 1024
#define TOT_ELEMS (32 * HW * EMB_DIM)   // 33554432

typedef __attribute__((ext_vector_type(4))) float f32x4;
typedef unsigned long long u64;

// ws layout (bytes)
#define WS_EMBQ_OFF 0             // 256 KB fp8(e4m3) swizzled emb, 16 chunks x 16KB
#define WS_E2_OFF   262144        // 1024 f32 ||e||^2 (fp32-exact)
#define WS_PSC_OFF  266240        // 1024 f32 block partials

#define MAIN_BLOCKS 1024          // 128 rows/block, 4 waves x 32 rows
#define ESCALE 65536.0f           // emb pre-scale: |e|<2^-10 -> |ê|<64 (normal e4m3)
#define INV2SCALE 3.0517578125e-5f // 2/65536, exact fp32

typedef const __attribute__((address_space(1))) unsigned int* gas_u32p;
typedef __attribute__((address_space(3))) unsigned int* las_u32p;
__device__ __forceinline__ void gll16(const void* g, void* l) {
    __builtin_amdgcn_global_load_lds((gas_u32p)g, (las_u32p)l, 16, 0, 0);
}

// ---------------------------------------------------------------------------
// Kernel 0: emb fp32 -> fp8 e4m3 (x65536), swizzled chunk layout + e2=||e||^2.
// chunk = e>>6 (64 e per 16KB chunk), row el = e&63 (256B rows),
// byte cb within row stored at cb ^ ((el&15)<<3)  [bits 6:3 XOR row]:
// puts the reader's ds_read_b64 at the 4-lane/bank-pair floor.
// ---------------------------------------------------------------------------
__global__ __launch_bounds__(64) void prep_emb(const float* __restrict__ emb,
                                               char* __restrict__ embq,
                                               float* __restrict__ e2) {
    const int e = blockIdx.x, ln = threadIdx.x;
    const float4 v = reinterpret_cast<const float4*>(emb)[e * 64 + ln];
    float s = v.x * v.x + v.y * v.y + v.z * v.z + v.w * v.w;

    unsigned d = 0;
    d = (unsigned)__builtin_amdgcn_cvt_pk_fp8_f32(v.x * ESCALE, v.y * ESCALE, (int)d, false);
    d = (unsigned)__builtin_amdgcn_cvt_pk_fp8_f32(v.z * ESCALE, v.w * ESCALE, (int)d, true);

    const int el = e & 63, ch = e >> 6;
    const int cb = (ln * 4) ^ ((el & 15) << 3);
    *reinterpret_cast<unsigned*>(embq + ch * 16384 + el * 256 + cb) = d;

#pragma unroll
    for (int o = 32; o; o >>= 1) s += __shfl_down(s, o);
    if (ln == 0) e2[e] = s;
}

// ---------------------------------------------------------------------------
// Kernel 1: fused copy + sum(x^2) + fp8 GEMM + min-reduction.
// 4 waves x 32 rows/wave; x-fragments quantized to fp8 (32 AGPRs, pinned via
// asm "+a" — R4/R6-verified spill fix at HALF the register cost of bf16).
// emb: 16KB fp8 chunks double-buffered (32KB LDS), global_load_lds from the
// pre-swizzled source; 1 barrier/chunk. Target: 4 waves/SIMD, 4 blocks/CU.
// MFMA 16x16x32 fp8_fp8: A=emb^ (LDS), B=x^ (AGPR);
// D[e][m]: m=lane&15, e=4*(lane>>4)+reg.  score = e2 - 2^-15 * (A.B)
// ---------------------------------------------------------------------------
__global__ __launch_bounds__(256)
void vq_main(const float* __restrict__ x,
             float* __restrict__ out,
             const char* __restrict__ embq,
             const float* __restrict__ e2,
             float* __restrict__ psc) {
    __shared__ char smem[32768];           // 2 x 16KB emb chunk buffers
    const int tid = threadIdx.x;
    const int wv = tid >> 6, ln = tid & 63;
    const int u = ln & 15, g = ln >> 4;    // m-lane, k-octet group

    const int row_base = blockIdx.x << 7;  // 128 rows/block
    const int b = row_base >> 12, n_base = row_base & 4095;
    const unsigned base0 = (unsigned)(b * (EMB_DIM * HW) + n_base + wv * 32 + u);

    // ---- stage emb chunk 0 (overlaps the x prologue) ----
    {
        const char* gs = embq + wv * 4096 + ln * 16;
        char* lb = smem + wv * 4096;
#pragma unroll
        for (int i = 0; i < 4; ++i) gll16(gs + i * 1024, lb + i * 1024);
    }

    // ---- load x once: copy to out, accumulate x^2, build fp8 B-fragments.
    //      Fenced per kf (16 loads in flight) to cap register demand. ----
    float x2s = 0.f;
    long long bx0[8], bx1[8];

#define LDJ(KF, JP, WREG, ZREG, HI) do {                                       \
    const unsigned o_ = base0 + (unsigned)((((KF) * 32 + g * 8 + 2 * (JP))) * HW); \
    const float fa0_ = x[o_],      fb0_ = x[o_ + 16];                          \
    const float fa1_ = x[o_ + HW], fb1_ = x[o_ + HW + 16];                     \
    out[o_] = fa0_;       out[o_ + 16] = fb0_;                                 \
    out[o_ + HW] = fa1_;  out[o_ + HW + 16] = fb1_;                            \
    x2s += fa0_ * fa0_ + fb0_ * fb0_ + fa1_ * fa1_ + fb1_ * fb1_;              \
    WREG = (unsigned)__builtin_amdgcn_cvt_pk_fp8_f32(fa0_, fa1_, (int)WREG, HI); \
    ZREG = (unsigned)__builtin_amdgcn_cvt_pk_fp8_f32(fb0_, fb1_, (int)ZREG, HI); \
} while (0)

#pragma unroll
    for (int kf = 0; kf < 8; ++kf) {
        unsigned w0 = 0, w1 = 0, z0 = 0, z1 = 0;
        LDJ(kf, 0, w0, z0, false);
        LDJ(kf, 1, w0, z0, true);
        LDJ(kf, 2, w1, z1, false);
        LDJ(kf, 3, w1, z1, true);
        bx0[kf] = (long long)(((u64)w1 << 32) | w0);
        bx1[kf] = (long long)(((u64)z1 << 32) | z0);
        // pin persistent fragments into AGPRs (R4/R6-verified: kills spills)
        asm volatile("" : "+a"(bx0[kf]), "+a"(bx1[kf]));
        __builtin_amdgcn_sched_barrier(0);   // no load hoisting across kf groups
    }
#undef LDJ

    __syncthreads();   // chunk 0 staged (barrier drains vmcnt)

    float b0 = 3.0e38f, b1 = 3.0e38f;
    const int swz = u << 3;                // (el&15)<<3 with el=t*16+u

    for (int c = 0; c < 16; ++c) {
        if (c < 15) {  // stage next 16KB chunk into the other buffer
            const char* gs = embq + (c + 1) * 16384 + wv * 4096 + ln * 16;
            char* lb = smem + ((c + 1) & 1) * 16384 + wv * 4096;
#pragma unroll
            for (int i = 0; i < 4; ++i) gll16(gs + i * 1024, lb + i * 1024);
        }
        const char* bufb = smem + (c & 1) * 16384;
#pragma unroll
        for (int t = 0; t < 4; ++t) {
            const int rowb = (t * 16 + u) * 256;
            f32x4 a0 = {0.f, 0.f, 0.f, 0.f}, a1 = a0;
#pragma unroll
            for (int kf = 0; kf < 8; ++kf) {
                const int off = rowb + ((kf * 32 + g * 8) ^ swz);
                const long long av = *reinterpret_cast<const long long*>(bufb + off);
                a0 = __builtin_amdgcn_mfma_f32_16x16x32_fp8_fp8(av, bx0[kf], a0, 0, 0, 0);
                a1 = __builtin_amdgcn_mfma_f32_16x16x32_fp8_fp8(av, bx1[kf], a1, 0, 0, 0);
            }
            const f32x4 ev = *reinterpret_cast<const f32x4*>(e2 + c * 64 + t * 16 + g * 4);
#pragma unroll
            for (int r = 0; r < 4; ++r) {
                b0 = fminf(b0, fmaf(-INV2SCALE, a0[r], ev[r]));
                b1 = fminf(b1, fmaf(-INV2SCALE, a1[r], ev[r]));
            }
        }
        __syncthreads();   // all waves done with bufb; gll(c+1) drained
    }

    // combine the 4 g-lane copies (each saw a disjoint quarter of the e's)
    b0 = fminf(b0, __shfl_xor(b0, 16));
    b0 = fminf(b0, __shfl_xor(b0, 32));
    b1 = fminf(b1, __shfl_xor(b1, 16));
    b1 = fminf(b1, __shfl_xor(b1, 32));

    float contrib = x2s + ((g == 0) ? (b0 + b1) : 0.f);
#pragma unroll
    for (int o = 32; o; o >>= 1) contrib += __shfl_down(contrib, o);

    float* wsf = reinterpret_cast<float*>(smem);   // safe: post-loop barrier
    if (ln == 0) wsf[wv] = contrib;
    __syncthreads();
    if (tid == 0) psc[blockIdx.x] = (wsf[0] + wsf[1]) + (wsf[2] + wsf[3]);
}

// ---------------------------------------------------------------------------
// Kernel 2: deterministic tree-reduce of partials -> loss scalar.
// ---------------------------------------------------------------------------
__global__ __launch_bounds__(256) void finalize(const float* __restrict__ psc,
                                                float* __restrict__ out_loss) {
    __shared__ float red[256];
    const int t = threadIdx.x;
    float s = 0.f;
#pragma unroll
    for (int i = 0; i < MAIN_BLOCKS / 256; ++i) s += psc[t + i * 256];
    red[t] = s;
    __syncthreads();
    for (int h = 128; h; h >>= 1) {
        if (t < h) red[t] += red[t + h];
        __syncthreads();
    }
    if (t == 0) *out_loss = 1.25f * red[0] / (float)TOT_ELEMS;
}

extern "C" void kernel_launch(void* const* d_in, const int* in_sizes, int n_in,
                              void* d_out, int out_size, void* d_ws, size_t ws_size,
                              hipStream_t stream) {
    const float* x = (const float*)d_in[0];
    const float* emb = (const float*)d_in[1];
    float* out = (float*)d_out;
    char* ws = (char*)d_ws;

    char*  embq = ws + WS_EMBQ_OFF;
    float* e2   = (float*)(ws + WS_E2_OFF);
    float* psc  = (float*)(ws + WS_PSC_OFF);

    prep_emb<<<N_EMB, 64, 0, stream>>>(emb, embq, e2);
    vq_main<<<MAIN_BLOCKS, 256, 0, stream>>>(x, out, embq, e2, psc);
    finalize<<<1, 256, 0, stream>>>(psc, out + TOT_ELEMS);
}